// Round 6
// baseline (91.291 us; speedup 1.0000x reference)
//
#include <hip/hip_runtime.h>

// SNN 2->8->8->1, 16 steps, leak=0.8, thr=0.5.
// R17 = MEASUREMENT ROUND (deliberate; revert to R16 structure in R18).
//
// Why: 5 consecutive nulls (R11 25.2 | R13 26.4 | R15 25.4 | R16 25.2;
// R12/R14 regress via +VALU). R16 proved: not DS-instr-bound (3x fewer
// DS instrs, same time), not schedule-bound (R13/R15), and the pipe
// arithmetic leaves ~10us unexplained. Also: the SNN kernel has NEVER
// appeared in the top-5 counter rows (39us poison-fills outrank 25us).
// Design, one round, three readouts:
//  1) Time-amplification bisect: run the bitwise-identical 16-step loop
//     5x (A/A2 are read-only in the unrolled loop). dur ~= P + 5L with
//     P + L = 25.2 -> solves preamble P and loop L separately.
//     DCE defeated per skill rule #17: opaque asm "+v" touch on A/A2 at
//     rep top (defeats cross-rep CSE), keep-alive asm on tot/mo/m2[] at
//     rep bottom. Output = last rep -> bit-exact, absmax 0.0.
//  2) At ~60-100us the kernel is top-1 in the counter table -> first
//     look at its VGPR_Count (is the (256,8) 64-VGPR cap spilling?),
//     SQ_LDS_BANK_CONFLICT, VALUBusy, FETCH_SIZE (no-spill ideal
//     ~4.3MB; >>10MB => scratch spills are the hidden cost).
// Prediction: dur ~77us (L~13, P~12); VGPR=64; FETCH~4.3MB.
// R18 decision tree: FETCH>>10MB -> fix spills (relax cap / trim
// preamble); conflicts dominant -> conflict engineering; VALUBusy>70%
// & L small -> attack 256-instr trn block (B_t monotone -> bin-search).
//
// Bit-exactness: every rep computes identical values; final rep's tot
// is the R16 answer verbatim. asm statements are empty (no value change).

// ---- compile-time breakpoint search (bit-exact f32, IEEE RN per op) ----
constexpr bool spikes_by(float c, int p) {
    float m = 0.f;
    for (int t = 0; t < p; ++t) {
        float a = 0.8f * m;
        m = a + c;
        if (m >= 0.5f) return true;
    }
    return false;
}
constexpr unsigned find_B(int p) {
    unsigned lo = 0x3D4CCCCDu;  // 0.05f: never spikes
    unsigned hi = 0x3F19999Au;  // 0.6f : spikes at step 1
    while (hi - lo > 1u) {
        unsigned mid = lo + (hi - lo) / 2u;
        if (spikes_by(__builtin_bit_cast(float, mid), p)) hi = mid;
        else lo = mid;
    }
    return hi;
}
constexpr float kB[17] = {
    0.f,
    __builtin_bit_cast(float, find_B(1)),  __builtin_bit_cast(float, find_B(2)),
    __builtin_bit_cast(float, find_B(3)),  __builtin_bit_cast(float, find_B(4)),
    __builtin_bit_cast(float, find_B(5)),  __builtin_bit_cast(float, find_B(6)),
    __builtin_bit_cast(float, find_B(7)),  __builtin_bit_cast(float, find_B(8)),
    __builtin_bit_cast(float, find_B(9)),  __builtin_bit_cast(float, find_B(10)),
    __builtin_bit_cast(float, find_B(11)), __builtin_bit_cast(float, find_B(12)),
    __builtin_bit_cast(float, find_B(13)), __builtin_bit_cast(float, find_B(14)),
    __builtin_bit_cast(float, find_B(15)), __builtin_bit_cast(float, find_B(16))
};
constexpr unsigned mk_train(int F) {
    unsigned tr = 0;
    if (F <= 16) for (int t = F; t <= 16; t += F) tr |= 1u << (t - 1);
    return tr;
}
constexpr unsigned kTv[18] = {
    0, mk_train(1), mk_train(2),  mk_train(3),  mk_train(4),  mk_train(5),
    mk_train(6),  mk_train(7),  mk_train(8),  mk_train(9),  mk_train(10),
    mk_train(11), mk_train(12), mk_train(13), mk_train(14), mk_train(15),
    mk_train(16), mk_train(17)
};

__device__ __forceinline__ unsigned long long tr8(unsigned long long x) {
    unsigned long long t;
    t = (x ^ (x >> 7))  & 0x00AA00AA00AA00AAull; x = x ^ t ^ (t << 7);
    t = (x ^ (x >> 14)) & 0x0000CCCC0000CCCCull; x = x ^ t ^ (t << 14);
    t = (x ^ (x >> 28)) & 0x00000000F0F0F0F0ull; x = x ^ t ^ (t << 28);
    return x;
}

__global__ __launch_bounds__(256, 8) void snn_kernel(
    const float* __restrict__ x,
    const float* __restrict__ W_ih, const float* __restrict__ b_ih,
    const float* __restrict__ W_hh, const float* __restrict__ b_hh,
    const float* __restrict__ W_ho, const float* __restrict__ b_ho,
    float* __restrict__ out, int n)
{
#pragma clang fp contract(off)
    __shared__ __align__(16) float lut2[256 * 12];   // 12 KB, stride 12
    __shared__ float luto[256];                      // 1 KB
    __shared__ unsigned Tv[18];

    const int p = threadIdx.x;

    {   // lut2 + luto: entry q, neuron k at bit k (LSB), exact fma chains
        float bits[8];
#pragma unroll
        for (int k = 0; k < 8; ++k) bits[k] = (float)((p >> k) & 1);
        float e[8];
#pragma unroll
        for (int j = 0; j < 8; ++j) {
            float acc = 0.f;
#pragma unroll
            for (int k = 0; k < 8; ++k)
                acc = __fmaf_rn(bits[k], W_hh[8 * j + k], acc);
            e[j] = acc;
        }
        float4* dst = reinterpret_cast<float4*>(&lut2[p * 12]);
        dst[0] = make_float4(e[0], e[1], e[2], e[3]);
        dst[1] = make_float4(e[4], e[5], e[6], e[7]);
        float acc = 0.f;
#pragma unroll
        for (int k = 0; k < 8; ++k)
            acc = __fmaf_rn(bits[k], W_ho[k], acc);
        luto[p] = acc;
    }
    if (p < 18) Tv[p] = kTv[p];
    __syncthreads();

    const int i = blockIdx.x * 256 + p;
    if (i >= n) return;

    const float2 xv = reinterpret_cast<const float2*>(x)[i];
    float cur[8];
#pragma unroll
    for (int j = 0; j < 8; ++j) {
        float d = __fmaf_rn(xv.y, W_ih[2 * j + 1], __fmul_rn(xv.x, W_ih[2 * j]));
        cur[j] = __fadd_rn(d, b_ih[j]);
    }

    // F = 1 + #{t: c < B_t}; B_t compile-time literals. train = Tv[F]
    unsigned trn[8];
#pragma unroll
    for (int j = 0; j < 8; ++j) {
        float c = cur[j];
        unsigned cnt = 0;
#pragma unroll
        for (int t = 1; t <= 16; ++t)
            cnt += (c < kB[t]) ? 1u : 0u;
        trn[j] = Tv[cnt + 1u];
    }

    // 8x16 bit transpose -> step bytes (byte t = step t, bit j = neuron j)
    unsigned long long A = 0, A2 = 0;
#pragma unroll
    for (int j = 0; j < 8; ++j) {
        A  |= (unsigned long long)(trn[j] & 0xFFu) << (8 * j);
        A2 |= (unsigned long long)((trn[j] >> 8) & 0xFFu) << (8 * j);
    }
    A = tr8(A); A2 = tr8(A2);

    float bh[8];
#pragma unroll
    for (int j = 0; j < 8; ++j) bh[j] = b_hh[j];
    const float bho = b_ho[0];

    float m2[8];
    float mo, odP;
    unsigned tot = 0;

    // ---- 5 reps of the identical 16-step loop (measurement amplifier).
    // A/A2 are read-only inside (static bfe extracts); opaque touch
    // prevents cross-rep CSE; keep-alive prevents DCE of reps 0..3.
#pragma unroll 1
    for (int rep = 0; rep < 5; ++rep) {
        asm volatile("" : "+v"(A), "+v"(A2));   // inputs "change" per rep

#pragma unroll
        for (int j = 0; j < 8; ++j) m2[j] = 0.f;
        mo = 0.f; odP = 0.f; tot = 0;

        float4 dvlo[2], dvhi[2];
        {   // prologue: issue dv_0, dv_1
            const unsigned b0 = (unsigned)(A) & 0xFFu;
            const float4* e0 = reinterpret_cast<const float4*>(&lut2[b0 * 12]);
            dvlo[0] = e0[0]; dvhi[0] = e0[1];
            const unsigned b1 = (unsigned)(A >> 8) & 0xFFu;
            const float4* e1 = reinterpret_cast<const float4*>(&lut2[b1 * 12]);
            dvlo[1] = e1[0]; dvhi[1] = e1[1];
        }

#pragma unroll
        for (int t = 0; t < 16; ++t) {
            float dvf[8];
            dvf[0] = dvlo[t & 1].x; dvf[1] = dvlo[t & 1].y;
            dvf[2] = dvlo[t & 1].z; dvf[3] = dvlo[t & 1].w;
            dvf[4] = dvhi[t & 1].x; dvf[5] = dvhi[t & 1].y;
            dvf[6] = dvhi[t & 1].z; dvf[7] = dvhi[t & 1].w;

            unsigned mk2 = 0;
#pragma unroll
            for (int j = 7; j >= 0; --j) {
                float m = __fadd_rn(__fadd_rn(__fmul_rn(0.8f, m2[j]), dvf[j]), bh[j]);
                bool s = (m >= 0.5f);
                mk2 = 2u * mk2 + (s ? 1u : 0u);
                m2[j] = s ? 0.f : m;
            }

            if (t + 2 < 16) {
                const int tn = t + 2;
                const unsigned bN = (tn < 8)
                    ? ((unsigned)(A  >> (8 * tn)) & 0xFFu)
                    : ((unsigned)(A2 >> (8 * (tn - 8))) & 0xFFu);
                const float4* en = reinterpret_cast<const float4*>(&lut2[bN * 12]);
                dvlo[t & 1] = en[0];
                dvhi[t & 1] = en[1];
            }

            if (t > 0) {
                float m = __fadd_rn(__fadd_rn(__fmul_rn(0.8f, mo), odP), bho);
                bool s = (m >= 0.5f);
                tot += s ? 1u : 0u;
                mo = s ? 0.f : m;
            }

            odP = luto[mk2];
        }
        {   // epilogue: output update for step 15
            float m = __fadd_rn(__fadd_rn(__fmul_rn(0.8f, mo), odP), bho);
            tot += (m >= 0.5f) ? 1u : 0u;
        }

        // keep this rep's results live (defeats DCE of reps 0..3)
        asm volatile("" :: "v"(tot), "v"(mo),
                     "v"(m2[0]), "v"(m2[1]), "v"(m2[2]), "v"(m2[3]),
                     "v"(m2[4]), "v"(m2[5]), "v"(m2[6]), "v"(m2[7]));
    }

    out[i] = __fmul_rn((float)tot, 0.0625f);
}

extern "C" void kernel_launch(void* const* d_in, const int* in_sizes, int n_in,
                              void* d_out, int out_size, void* d_ws, size_t ws_size,
                              hipStream_t stream) {
    const float* x    = (const float*)d_in[0];
    const float* W_ih = (const float*)d_in[1];
    const float* b_ih = (const float*)d_in[2];
    const float* W_hh = (const float*)d_in[3];
    const float* b_hh = (const float*)d_in[4];
    const float* W_ho = (const float*)d_in[5];
    const float* b_ho = (const float*)d_in[6];
    float* out = (float*)d_out;

    const int n = out_size;  // 524288
    const int block = 256;
    const int grid = (n + block - 1) / block;  // 2048
    snn_kernel<<<grid, block, 0, stream>>>(x, W_ih, b_ih, W_hh, b_hh,
                                           W_ho, b_ho, out, n);
}